// Round 9
// baseline (475.581 us; speedup 1.0000x reference)
//
#include <hip/hip_runtime.h>

// QJLKeyCache: out = softmax_rows(EST * norms[n] * (Q @ S^T) @ K^T)
// B=2048, D=128, M=256, NKEYS=32768.
// Round 12: offset-softmax one-pass (drop the 2nd GEMM).
// Evidence (r8 bench): 2-phase dbuf NEUTRAL (409->421) — pipeline scheduling
// is not the lever. All our kernels <162us (hidden under harness fills);
// two GEMM passes ~150-160us each (~220 TF, ~9% MfmaUtil), cause unknown.
// Softmax is shift-invariant: use per-row conservative offset
//   C0[row] = 4.5 * EST * maxnorm * ||pq_row||_2   (= 4.5 sigma, exact var)
// so pass 1 writes exp(s - C0) directly + per-(row,cb) sums; combine gives
// 1/L; a streaming pass scales in place. Clamp exp arg at 80 and L at 1e-30
// for unconditional fp32 safety. Single GEMM (~180-200us incl 256MB store)
// now EXCEEDS the 162us fills -> its PMC counters become visible (diagnosis).

#define NB 2048
#define DD 128
#define MM 256
#define NK 32768
// sqrt(pi/2)/256
#define EST_CONST 4.8957583489668673e-03f
#define C0_SIGMAS 4.5f

typedef _Float16 half8 __attribute__((ext_vector_type(8)));
typedef _Float16 half4v __attribute__((ext_vector_type(4)));
typedef float floatx4 __attribute__((ext_vector_type(4)));

__device__ __forceinline__ void async16(const void* g, void* l) {
    __builtin_amdgcn_global_load_lds(
        (const __attribute__((address_space(1))) unsigned int*)g,
        (__attribute__((address_space(3))) unsigned int*)l,
        16, 0, 0);
}

// K1: proj[b][m] = sum_d query[b][d]*sketch[m][d] (fp16) + pqnorm[b] = ||pq||_2.
__global__ void proj_kernel(const float* __restrict__ query,
                            const float* __restrict__ sketch,
                            _Float16* __restrict__ proj,
                            float* __restrict__ pqnorm) {
    __shared__ float q[DD];
    __shared__ float red[4];
    const int b = blockIdx.x;
    const int t = threadIdx.x;
    if (t < DD) q[t] = query[b * DD + t];
    __syncthreads();
    const float* srow = sketch + t * DD;   // t = m in [0,256)
    float acc = 0.f;
#pragma unroll
    for (int d = 0; d < DD; d += 4) {
        float4 s4 = *(const float4*)(srow + d);
        acc += s4.x * q[d] + s4.y * q[d + 1] + s4.z * q[d + 2] + s4.w * q[d + 3];
    }
    proj[b * MM + t] = (_Float16)acc;
    // block-reduce sum of squares -> pqnorm
    float ss = acc * acc;
#pragma unroll
    for (int d = 1; d < 64; d <<= 1) ss += __shfl_xor(ss, d, 64);
    if ((t & 63) == 0) red[t >> 6] = ss;
    __syncthreads();
    if (t == 0) pqnorm[b] = sqrtf(red[0] + red[1] + red[2] + red[3]);
}

// K2: cached_keys fp32 (+-1) -> fp16 (exact); block 8192 computes maxnorm.
__global__ void cvt_keys(const float* __restrict__ keys, _Float16* __restrict__ kh,
                         const float* __restrict__ norms, float* __restrict__ maxnorm) {
    if (blockIdx.x == 8192) {
        __shared__ float r[4];
        const float4* n4 = (const float4*)norms;
        float m = 0.f;
        for (int i = threadIdx.x; i < NK / 4; i += 256) {
            float4 v = n4[i];
            m = fmaxf(fmaxf(m, fmaxf(v.x, v.y)), fmaxf(v.z, v.w));
        }
#pragma unroll
        for (int d = 1; d < 64; d <<= 1) m = fmaxf(m, __shfl_xor(m, d, 64));
        if ((threadIdx.x & 63) == 0) r[threadIdx.x >> 6] = m;
        __syncthreads();
        if (threadIdx.x == 0)
            maxnorm[0] = fmaxf(fmaxf(r[0], r[1]), fmaxf(r[2], r[3]));
        return;
    }
    const int i = blockIdx.x * 256 + threadIdx.x;   // one float4 per thread
    float4 v = ((const float4*)keys)[i];
    half4v h;
    h.x = (_Float16)v.x; h.y = (_Float16)v.y; h.z = (_Float16)v.z; h.w = (_Float16)v.w;
    ((half4v*)kh)[i] = h;
}

// K3: 128x128 tile GEMM (single-buffer r4-measured k-loop), fp16 MFMA.
// Epilogue: e = exp(min(s - C0[row], 80)) -> fp32 out store + per-(row,cb)
// sum -> ssum. No max pass, no recompute pass.
__global__ __launch_bounds__(256, 3)
void gemm_exp_kernel(const _Float16* __restrict__ proj,   // [2048][256]
                     const _Float16* __restrict__ kh,     // [32768][256]
                     const float* __restrict__ key_norms,
                     const float* __restrict__ pqnorm,    // [2048]
                     const float* __restrict__ maxnorm,   // [1]
                     float* __restrict__ out,             // [2048][32768]
                     float* __restrict__ ssum) {          // [2048][256]
    __shared__ __align__(16) _Float16 smem[16384];   // sQ(16KB) + sK(16KB)
    __shared__ float redS[128][2];
    _Float16* sQ = smem;
    _Float16* sK = smem + 8192;

    const int tid  = threadIdx.x;
    const int lane = tid & 63;
    const int wave = tid >> 6;
    const int quad = lane >> 4;
    const int lc   = lane & 15;
    const int wb   = wave >> 1;   // b-row 64-strip
    const int wn   = wave & 1;    // key-col 64-strip
    const int cb      = blockIdx.x;         // key col-block (fastest -> XCD owns keys)
    const int colBase = cb * 128;
    const int rowBase = blockIdx.y * 128;   // batch rows

    floatx4 acc[4][4];   // [ib][in]: C[b=wb*64+ib*16+lc][n=wn*64+in*16+quad*4+r]
#pragma unroll
    for (int i = 0; i < 4; i++)
#pragma unroll
        for (int j = 0; j < 4; j++) acc[i][j] = (floatx4){0.f, 0.f, 0.f, 0.f};

    // Staging: chunk c in [0,1024): LDS slot c*16B (wave-uniform + lane*16),
    // holds global (row=c>>3, seg=(c&7)^(row&7)) -- XOR swizzle balances the
    // ds_read_b128 bank pattern for the 128B row stride.
    const _Float16* gQ[4];
    const _Float16* gK[4];
    int ldsOff[4];
#pragma unroll
    for (int p = 0; p < 4; p++) {
        const int c = p * 256 + tid;
        const int row = c >> 3;
        const int seg = (c & 7) ^ (row & 7);
        gQ[p] = proj + (rowBase + row) * MM + seg * 8;
        gK[p] = kh + (colBase + row) * MM + seg * 8;
        ldsOff[p] = c * 8;
    }

    // per-row offset C0 = 4.5 * EST * maxnorm * ||pq_row||  (4 rows/thread)
    const float mn = maxnorm[0];
    float c0Row[4];
#pragma unroll
    for (int ib = 0; ib < 4; ib++)
        c0Row[ib] = C0_SIGMAS * EST_CONST * mn * pqnorm[rowBase + wb * 64 + ib * 16 + lc];

    for (int k0 = 0; k0 < MM; k0 += 64) {
        __syncthreads();
#pragma unroll
        for (int p = 0; p < 4; p++) {
            async16(gQ[p] + k0, &sQ[ldsOff[p]]);
            async16(gK[p] + k0, &sK[ldsOff[p]]);
        }
        __syncthreads();
#pragma unroll
        for (int kk = 0; kk < 2; kk++) {
            const int segSel = ((kk * 4 + quad) ^ (lc & 7)) * 8;
            half8 kf[4], qf[4];
#pragma unroll
            for (int s = 0; s < 4; s++) {
                kf[s] = *(const half8*)&sK[(wn * 64 + s * 16 + lc) * 64 + segSel];
                qf[s] = *(const half8*)&sQ[(wb * 64 + s * 16 + lc) * 64 + segSel];
            }
#pragma unroll
            for (int ib = 0; ib < 4; ib++)
#pragma unroll
                for (int in = 0; in < 4; in++)
                    acc[ib][in] = __builtin_amdgcn_mfma_f32_16x16x32_f16(
                        kf[in], qf[ib], acc[ib][in], 0, 0, 0);
        }
    }

    // scale: s = EST * norm[n] * inner ; n varies with (in, quad, r)
#pragma unroll
    for (int in = 0; in < 4; in++) {
        const float4 nrm = *(const float4*)&key_norms[colBase + wn * 64 + in * 16 + quad * 4];
#pragma unroll
        for (int ib = 0; ib < 4; ib++) {
            acc[ib][in][0] *= EST_CONST * nrm.x;
            acc[ib][in][1] *= EST_CONST * nrm.y;
            acc[ib][in][2] *= EST_CONST * nrm.z;
            acc[ib][in][3] *= EST_CONST * nrm.w;
        }
    }

    // e = exp(min(s - C0, 80)): fp32 store (16 rows x 64B sectors per instr,
    // 4 `in` iters complete 256B/row) + partial sums
#pragma unroll
    for (int ib = 0; ib < 4; ib++) {
        const int grow = rowBase + wb * 64 + ib * 16 + lc;
        const float c0 = c0Row[ib];
        float* orow = out + (size_t)grow * NK + colBase + wn * 64 + quad * 4;
        float sm = 0.f;
#pragma unroll
        for (int in = 0; in < 4; in++) {
            floatx4 o;
#pragma unroll
            for (int r = 0; r < 4; r++) {
                const float e = __expf(fminf(acc[ib][in][r] - c0, 80.f));
                o[r] = e;
                sm += e;
            }
            __builtin_nontemporal_store(o, (floatx4*)(orow + in * 16));
        }
        sm += __shfl_xor(sm, 16, 64);
        sm += __shfl_xor(sm, 32, 64);
        if (quad == 0) redS[wb * 64 + ib * 16 + lc][wn] = sm;
    }
    __syncthreads();   // redS visible
    if (wn == 0 && quad == 0) {
#pragma unroll
        for (int ib = 0; ib < 4; ib++) {
            const int rl = wb * 64 + ib * 16 + lc;
            ssum[(rowBase + rl) * 256 + cb] = redS[rl][0] + redS[rl][1];
        }
    }
}

// K4: rowScale[row] = 1 / sum_cb ssum[row][cb]. One wave per row.
__global__ void combine_stats(const float* __restrict__ ssum,
                              float* __restrict__ rowScale) {
    const int lane = threadIdx.x & 63;
    const int row = blockIdx.x * 4 + (threadIdx.x >> 6);
    const float4 sv = ((const float4*)(ssum + row * 256))[lane];
    float l = sv.x + sv.y + sv.z + sv.w;
#pragma unroll
    for (int d = 1; d < 64; d <<= 1) l += __shfl_xor(l, d, 64);
    if (lane == 0) rowScale[row] = 1.0f / fmaxf(l, 1e-30f);
}

// K5: out *= rowScale[row], in place. 4 blocks per row (row uniform/block);
// nontemporal read+write, 512 MB stream.
__global__ __launch_bounds__(256)
void scale_kernel(float* __restrict__ out, const float* __restrict__ rowScale) {
    const int row = blockIdx.x >> 2;            // 8192 blocks / 2048 rows
    const float sc = rowScale[row];
    floatx4* p = (floatx4*)out + (size_t)blockIdx.x * 2048 + threadIdx.x;
#pragma unroll
    for (int i = 0; i < 8; i++) {
        floatx4 v = __builtin_nontemporal_load(p + i * 256);
        v *= sc;
        __builtin_nontemporal_store(v, p + i * 256);
    }
}

extern "C" void kernel_launch(void* const* d_in, const int* in_sizes, int n_in,
                              void* d_out, int out_size, void* d_ws, size_t ws_size,
                              hipStream_t stream) {
    const float* query  = (const float*)d_in[0];   // [2048][128]
    const float* keys   = (const float*)d_in[1];   // [32768][256] (+-1)
    const float* norms  = (const float*)d_in[2];   // [32768]
    const float* sketch = (const float*)d_in[3];   // [256][128]
    float* out = (float*)d_out;                    // [2048][32768]

    char* ws = (char*)d_ws;
    const size_t MB = 1024 * 1024;
    _Float16* kh     = (_Float16*)(ws);                 // 16 MB
    _Float16* proj   = (_Float16*)(ws + 16 * MB);       // 1 MB
    float* ssum      = (float*)(ws + 17 * MB);          // 2 MB
    float* rowScale  = (float*)(ws + 19 * MB);          // 8 KB
    float* pqnorm    = (float*)(ws + 19 * MB + 65536);  // 8 KB
    float* maxnorm   = (float*)(ws + 19 * MB + 131072); // 4 B

    hipLaunchKernelGGL(proj_kernel, dim3(NB), dim3(256), 0, stream,
                       query, sketch, proj, pqnorm);
    hipLaunchKernelGGL(cvt_keys, dim3(NK * MM / 4 / 256 + 1), dim3(256), 0, stream,
                       keys, kh, norms, maxnorm);
    hipLaunchKernelGGL(gemm_exp_kernel, dim3(NK / 128, NB / 128), dim3(256), 0, stream,
                       proj, kh, norms, pqnorm, maxnorm, out, ssum);
    hipLaunchKernelGGL(combine_stats, dim3(NB / 4), dim3(256), 0, stream,
                       ssum, rowScale);
    hipLaunchKernelGGL(scale_kernel, dim3(8192), dim3(256), 0, stream,
                       out, rowScale);
}

// Round 11
// 420.815 us; speedup vs baseline: 1.1301x; 1.1301x over previous
//
#include <hip/hip_runtime.h>

// QJLKeyCache: out = softmax_rows(EST * norms[n] * (Q @ S^T) @ K^T)
// B=2048, D=128, M=256, NKEYS=32768.
// Round 14 == round 13 resubmission (acquisition timeout; 256^2 kernel
// still unmeasured — no blind changes stacked).
// Evidence: r9 one-pass REGRESSED (475; scale pass 3.3 TB/s). r4 structure
// best (409). Deduced: ~160us harness fill INSIDE timed region; our kernels
// ~250us: stats~92, out~133, prep~25. GEMM at 92us = 6.5x compute-only
// (13.8us) -> stage-stall bound at 128^2 (16 MFMA/wave per 32KB staged).
// Change: 256^2 tile, 8 waves (512 thr), BK=64, acc[4][8] (128 VGPR),
// 1 blk/CU, 128KB LDS dbuf + 2-phase prefetch (only hiding at 1 blk/CU).
// Per k-step/SIMD: 128 MFMA (~2480cy) vs 64KB stage -> compute-dominated.
// Epilogues = direct generalization of r4-verified code (in 4->8, wn*128).
// Predicted: stats ~30, out ~75, total 409 -> ~290-310.

#define NB 2048
#define DD 128
#define MM 256
#define NK 32768
// sqrt(pi/2)/256
#define EST_CONST 4.8957583489668673e-03f

typedef _Float16 half8 __attribute__((ext_vector_type(8)));
typedef _Float16 half4v __attribute__((ext_vector_type(4)));
typedef float floatx4 __attribute__((ext_vector_type(4)));

#define BUF_HALVES 32768   // one k-step buffer: sQ 16384 + sK 16384 halves (64KB)

__device__ __forceinline__ void async16(const void* g, void* l) {
    __builtin_amdgcn_global_load_lds(
        (const __attribute__((address_space(1))) unsigned int*)g,
        (__attribute__((address_space(3))) unsigned int*)l,
        16, 0, 0);
}

// K1: proj[b][m] = sum_d query[b][d]*sketch[m][d], stored fp16.
__global__ void proj_kernel(const float* __restrict__ query,
                            const float* __restrict__ sketch,
                            _Float16* __restrict__ proj) {
    __shared__ float q[DD];
    const int b = blockIdx.x;
    const int t = threadIdx.x;
    if (t < DD) q[t] = query[b * DD + t];
    __syncthreads();
    const float* srow = sketch + t * DD;   // t = m in [0,256)
    float acc = 0.f;
#pragma unroll
    for (int d = 0; d < DD; d += 4) {
        float4 s4 = *(const float4*)(srow + d);
        acc += s4.x * q[d] + s4.y * q[d + 1] + s4.z * q[d + 2] + s4.w * q[d + 3];
    }
    proj[b * MM + t] = (_Float16)acc;
}

// K2: cached_keys fp32 (+-1) -> fp16 (exact).
__global__ void cvt_keys(const float* __restrict__ keys, _Float16* __restrict__ kh) {
    const int i = blockIdx.x * 256 + threadIdx.x;   // one float4 per thread
    float4 v = ((const float4*)keys)[i];
    half4v h;
    h.x = (_Float16)v.x; h.y = (_Float16)v.y; h.z = (_Float16)v.z; h.w = (_Float16)v.w;
    ((half4v*)kh)[i] = h;
}

// ---- 256^2-tile GEMM core, 8 waves (4 row-strips x 2 col-strips) ----
// Wave (wb,wn): rows wb*64..+64, cols wn*128..+128. acc[ib][in]:
// C[row = wb*64+ib*16+lc][col = wn*128+in*16+quad*4+r].
// Staging: chunk c in [0,2048)/array: LDS slot c*16B (wave-uniform+lane*16),
// holds global (row=c>>3, seg=(c&7)^(row&7)); read XOR on segSel matches.
// 2-phase dbuf: issue step t+1 loads before computing step t.

// K3 (S1): stats pass. Epilogue: per-row block-local max + sum(exp).
__global__ __launch_bounds__(512, 2)
void stats_kernel(const _Float16* __restrict__ proj,   // [2048][256]
                  const _Float16* __restrict__ kh,     // [32768][256]
                  const float* __restrict__ key_norms,
                  float* __restrict__ stats_max,       // [2048][128]
                  float* __restrict__ stats_sum) {     // [2048][128]
    __shared__ __align__(16) _Float16 smem[2 * BUF_HALVES];   // 128 KB dbuf
    __shared__ float red[256][2];
    __shared__ float redS[256][2];

    const int tid  = threadIdx.x;
    const int lane = tid & 63;
    const int wave = tid >> 6;      // [0,8)
    const int quad = lane >> 4;
    const int lc   = lane & 15;
    const int wb   = wave >> 1;     // [0,4) row 64-strip
    const int wn   = wave & 1;      // [0,2) col 128-strip
    const int cb      = blockIdx.x;        // key col-block (fastest)
    const int colBase = cb * 256;
    const int rowBase = blockIdx.y * 256;  // batch rows

    floatx4 acc[4][8];
#pragma unroll
    for (int i = 0; i < 4; i++)
#pragma unroll
        for (int j = 0; j < 8; j++) acc[i][j] = (floatx4){0.f, 0.f, 0.f, 0.f};

    const _Float16* gQ[4];
    const _Float16* gK[4];
    int qOff[4];
#pragma unroll
    for (int p = 0; p < 4; p++) {
        const int c = p * 512 + tid;        // [0,2048)
        const int row = c >> 3;             // [0,256)
        const int seg = (c & 7) ^ (row & 7);
        gQ[p] = proj + (rowBase + row) * MM + seg * 8;
        gK[p] = kh + (colBase + row) * MM + seg * 8;
        qOff[p] = c * 8;
    }

    // prologue: stage k-step 0 into buf 0
#pragma unroll
    for (int p = 0; p < 4; p++) {
        async16(gQ[p], &smem[qOff[p]]);
        async16(gK[p], &smem[16384 + qOff[p]]);
    }
    __syncthreads();

    int cur = 0;
#pragma unroll
    for (int t = 0; t < 4; ++t) {
        if (t < 3) {
            const int k0n = (t + 1) * 64;
            const int nb = (cur ^ 1) * BUF_HALVES;
#pragma unroll
            for (int p = 0; p < 4; p++) {
                async16(gQ[p] + k0n, &smem[nb + qOff[p]]);
                async16(gK[p] + k0n, &smem[nb + 16384 + qOff[p]]);
            }
        }
        const _Float16* sQ = smem + cur * BUF_HALVES;
        const _Float16* sK = sQ + 16384;
#pragma unroll
        for (int kk = 0; kk < 2; kk++) {
            const int segSel = ((kk * 4 + quad) ^ (lc & 7)) * 8;
            half8 kf[8], qf[4];
#pragma unroll
            for (int s = 0; s < 8; s++)
                kf[s] = *(const half8*)&sK[(wn * 128 + s * 16 + lc) * 64 + segSel];
#pragma unroll
            for (int s = 0; s < 4; s++)
                qf[s] = *(const half8*)&sQ[(wb * 64 + s * 16 + lc) * 64 + segSel];
#pragma unroll
            for (int ib = 0; ib < 4; ib++)
#pragma unroll
                for (int in = 0; in < 8; in++)
                    acc[ib][in] = __builtin_amdgcn_mfma_f32_16x16x32_f16(
                        kf[in], qf[ib], acc[ib][in], 0, 0, 0);
        }
        __syncthreads();
        cur ^= 1;
    }

    // scale: s = EST * norm[n] * inner
#pragma unroll
    for (int in = 0; in < 8; in++) {
        const float4 nrm = *(const float4*)&key_norms[colBase + wn * 128 + in * 16 + quad * 4];
#pragma unroll
        for (int ib = 0; ib < 4; ib++) {
            acc[ib][in][0] *= EST_CONST * nrm.x;
            acc[ib][in][1] *= EST_CONST * nrm.y;
            acc[ib][in][2] *= EST_CONST * nrm.z;
            acc[ib][in][3] *= EST_CONST * nrm.w;
        }
    }

    // per-row (256-col block-local) max
#pragma unroll
    for (int ib = 0; ib < 4; ib++) {
        float mx = -1e30f;
#pragma unroll
        for (int in = 0; in < 8; in++)
#pragma unroll
            for (int r = 0; r < 4; r++) mx = fmaxf(mx, acc[ib][in][r]);
        mx = fmaxf(mx, __shfl_xor(mx, 16, 64));
        mx = fmaxf(mx, __shfl_xor(mx, 32, 64));
        if (quad == 0) red[wb * 64 + ib * 16 + lc][wn] = mx;
    }
    __syncthreads();
    float mcb[4];
#pragma unroll
    for (int ib = 0; ib < 4; ib++) {
        const int rl = wb * 64 + ib * 16 + lc;
        mcb[ib] = fmaxf(red[rl][0], red[rl][1]);
    }
    // partial sums of exp(s - mcb)
#pragma unroll
    for (int ib = 0; ib < 4; ib++) {
        float sm = 0.f;
#pragma unroll
        for (int in = 0; in < 8; in++)
#pragma unroll
            for (int r = 0; r < 4; r++) sm += __expf(acc[ib][in][r] - mcb[ib]);
        sm += __shfl_xor(sm, 16, 64);
        sm += __shfl_xor(sm, 32, 64);
        if (quad == 0) redS[wb * 64 + ib * 16 + lc][wn] = sm;
    }
    __syncthreads();
    if (wn == 0 && quad == 0) {
#pragma unroll
        for (int ib = 0; ib < 4; ib++) {
            const int rl = wb * 64 + ib * 16 + lc;
            const int grow = rowBase + rl;
            stats_max[grow * 128 + cb] = mcb[ib];
            stats_sum[grow * 128 + cb] = redS[rl][0] + redS[rl][1];
        }
    }
}

// K4: per-row combine of 128 (m, l) -> rowC[row] = M + ln(L).
// One wave per row (4 rows/block); float2 per lane.
__global__ void combine_stats(const float* __restrict__ smax, const float* __restrict__ ssum,
                              float* __restrict__ rowC) {
    const int lane = threadIdx.x & 63;
    const int row = blockIdx.x * 4 + (threadIdx.x >> 6);
    const float2 mv = ((const float2*)(smax + row * 128))[lane];
    float m = fmaxf(mv.x, mv.y);
#pragma unroll
    for (int d = 1; d < 64; d <<= 1) m = fmaxf(m, __shfl_xor(m, d, 64));
    const float2 sv = ((const float2*)(ssum + row * 128))[lane];
    float l = sv.x * __expf(mv.x - m) + sv.y * __expf(mv.y - m);
#pragma unroll
    for (int d = 1; d < 64; d <<= 1) l += __shfl_xor(l, d, 64);
    if (lane == 0) rowC[row] = m + __logf(l);   // L >= 1 always
}

// K5 (S2): recompute GEMM (same core); epilogue exp(s - C) -> fp32 out.
__global__ __launch_bounds__(512, 2)
void out_kernel(const _Float16* __restrict__ proj,   // [2048][256]
                const _Float16* __restrict__ kh,     // [32768][256]
                const float* __restrict__ key_norms,
                const float* __restrict__ rowC,      // [2048]
                float* __restrict__ out) {           // [2048][32768]
    __shared__ __align__(16) _Float16 smem[2 * BUF_HALVES];   // 128 KB dbuf

    const int tid  = threadIdx.x;
    const int lane = tid & 63;
    const int wave = tid >> 6;
    const int quad = lane >> 4;
    const int lc   = lane & 15;
    const int wb   = wave >> 1;
    const int wn   = wave & 1;
    const int cb      = blockIdx.x;
    const int colBase = cb * 256;
    const int rowBase = blockIdx.y * 256;

    floatx4 acc[4][8];
#pragma unroll
    for (int i = 0; i < 4; i++)
#pragma unroll
        for (int j = 0; j < 8; j++) acc[i][j] = (floatx4){0.f, 0.f, 0.f, 0.f};

    const _Float16* gQ[4];
    const _Float16* gK[4];
    int qOff[4];
#pragma unroll
    for (int p = 0; p < 4; p++) {
        const int c = p * 512 + tid;
        const int row = c >> 3;
        const int seg = (c & 7) ^ (row & 7);
        gQ[p] = proj + (rowBase + row) * MM + seg * 8;
        gK[p] = kh + (colBase + row) * MM + seg * 8;
        qOff[p] = c * 8;
    }

    float cRow[4];
#pragma unroll
    for (int ib = 0; ib < 4; ib++)
        cRow[ib] = rowC[rowBase + wb * 64 + ib * 16 + lc];

#pragma unroll
    for (int p = 0; p < 4; p++) {
        async16(gQ[p], &smem[qOff[p]]);
        async16(gK[p], &smem[16384 + qOff[p]]);
    }
    __syncthreads();

    int cur = 0;
#pragma unroll
    for (int t = 0; t < 4; ++t) {
        if (t < 3) {
            const int k0n = (t + 1) * 64;
            const int nb = (cur ^ 1) * BUF_HALVES;
#pragma unroll
            for (int p = 0; p < 4; p++) {
                async16(gQ[p] + k0n, &smem[nb + qOff[p]]);
                async16(gK[p] + k0n, &smem[nb + 16384 + qOff[p]]);
            }
        }
        const _Float16* sQ = smem + cur * BUF_HALVES;
        const _Float16* sK = sQ + 16384;
#pragma unroll
        for (int kk = 0; kk < 2; kk++) {
            const int segSel = ((kk * 4 + quad) ^ (lc & 7)) * 8;
            half8 kf[8], qf[4];
#pragma unroll
            for (int s = 0; s < 8; s++)
                kf[s] = *(const half8*)&sK[(wn * 128 + s * 16 + lc) * 64 + segSel];
#pragma unroll
            for (int s = 0; s < 4; s++)
                qf[s] = *(const half8*)&sQ[(wb * 64 + s * 16 + lc) * 64 + segSel];
#pragma unroll
            for (int ib = 0; ib < 4; ib++)
#pragma unroll
                for (int in = 0; in < 8; in++)
                    acc[ib][in] = __builtin_amdgcn_mfma_f32_16x16x32_f16(
                        kf[in], qf[ib], acc[ib][in], 0, 0, 0);
        }
        __syncthreads();
        cur ^= 1;
    }

#pragma unroll
    for (int in = 0; in < 8; in++) {
        const float4 nrm = *(const float4*)&key_norms[colBase + wn * 128 + in * 16 + quad * 4];
#pragma unroll
        for (int ib = 0; ib < 4; ib++) {
            acc[ib][in][0] *= EST_CONST * nrm.x;
            acc[ib][in][1] *= EST_CONST * nrm.y;
            acc[ib][in][2] *= EST_CONST * nrm.z;
            acc[ib][in][3] *= EST_CONST * nrm.w;
        }
    }

    // out = exp(s - C), fp32, 16B/lane; 16 rows x 64B sectors per store instr
#pragma unroll
    for (int ib = 0; ib < 4; ib++) {
        const int grow = rowBase + wb * 64 + ib * 16 + lc;
        const float c = cRow[ib];
        float* orow = out + (size_t)grow * NK + colBase + wn * 128 + quad * 4;
#pragma unroll
        for (int in = 0; in < 8; in++) {
            floatx4 o;
#pragma unroll
            for (int r = 0; r < 4; r++)
                o[r] = __expf(acc[ib][in][r] - c);
            __builtin_nontemporal_store(o, (floatx4*)(orow + in * 16));
        }
    }
}

extern "C" void kernel_launch(void* const* d_in, const int* in_sizes, int n_in,
                              void* d_out, int out_size, void* d_ws, size_t ws_size,
                              hipStream_t stream) {
    const float* query  = (const float*)d_in[0];   // [2048][128]
    const float* keys   = (const float*)d_in[1];   // [32768][256] (+-1)
    const float* norms  = (const float*)d_in[2];   // [32768]
    const float* sketch = (const float*)d_in[3];   // [256][128]
    float* out = (float*)d_out;                    // [2048][32768]

    char* ws = (char*)d_ws;
    const size_t MB = 1024 * 1024;
    _Float16* kh   = (_Float16*)(ws);               // 16 MB
    _Float16* proj = (_Float16*)(ws + 16 * MB);     // 1 MB
    float* smax    = (float*)(ws + 17 * MB);        // 1 MB
    float* ssum    = (float*)(ws + 18 * MB);        // 1 MB
    float* rowC    = (float*)(ws + 19 * MB);        // 8 KB

    hipLaunchKernelGGL(proj_kernel, dim3(NB), dim3(256), 0, stream, query, sketch, proj);
    hipLaunchKernelGGL(cvt_keys, dim3(NK * MM / 4 / 256), dim3(256), 0, stream, keys, kh);
    hipLaunchKernelGGL(stats_kernel, dim3(NK / 256, NB / 256), dim3(512), 0, stream,
                       proj, kh, norms, smax, ssum);
    hipLaunchKernelGGL(combine_stats, dim3(NB / 4), dim3(256), 0, stream,
                       smax, ssum, rowC);
    hipLaunchKernelGGL(out_kernel, dim3(NK / 256, NB / 256), dim3(512), 0, stream,
                       proj, kh, norms, rowC, out);
}

// Round 12
// 404.939 us; speedup vs baseline: 1.1745x; 1.0392x over previous
//
#include <hip/hip_runtime.h>

// QJLKeyCache: out = softmax_rows(EST * norms[n] * (Q @ S^T) @ K^T)
// B=2048, D=128, M=256, NKEYS=32768.
// Round 15: revert to best-measured r4 structure (409.4us) + proj/cvt fusion.
// Accounting (r4/r8/r9/r11 benches): 2x 1-GiB poison fills per timed
// iteration = ~331us untouchable; our 5 kernels ~78-90us. GEMM schedule/tile
// variants (single-buf, dbuf, 256^2) all null => GEMMs are ~25-35us each;
// r4 single-buffer 128^2 was the best of the three. Floor ~388us
// (fills 331 + out store 41 + prep 14 + stats GEMM 22). This round: exact
// r4 GEMM/combine/out code; proj+cvt fused into one prep kernel (-1 launch).

#define NB 2048
#define DD 128
#define MM 256
#define NK 32768
// sqrt(pi/2)/256
#define EST_CONST 4.8957583489668673e-03f

typedef _Float16 half8 __attribute__((ext_vector_type(8)));
typedef _Float16 half4v __attribute__((ext_vector_type(4)));
typedef float floatx4 __attribute__((ext_vector_type(4)));

__device__ __forceinline__ void async16(const void* g, void* l) {
    __builtin_amdgcn_global_load_lds(
        (const __attribute__((address_space(1))) unsigned int*)g,
        (__attribute__((address_space(3))) unsigned int*)l,
        16, 0, 0);
}

// K1 (fused prep): blocks [0,8192): cached_keys fp32 (+-1) -> fp16 (exact).
// Blocks [8192,10240): proj[b][m] = sum_d query[b][d]*sketch[m][d], fp16.
__global__ void prep_kernel(const float* __restrict__ query,
                            const float* __restrict__ sketch,
                            const float* __restrict__ keys,
                            _Float16* __restrict__ proj,
                            _Float16* __restrict__ kh) {
    __shared__ float q[DD];
    const int t = threadIdx.x;
    if (blockIdx.x < 8192) {
        const int i = blockIdx.x * 256 + t;   // one float4 per thread
        float4 v = ((const float4*)keys)[i];
        half4v h;
        h.x = (_Float16)v.x; h.y = (_Float16)v.y; h.z = (_Float16)v.z; h.w = (_Float16)v.w;
        ((half4v*)kh)[i] = h;
        return;
    }
    const int b = blockIdx.x - 8192;
    if (t < DD) q[t] = query[b * DD + t];
    __syncthreads();
    const float* srow = sketch + t * DD;   // t = m in [0,256)
    float acc = 0.f;
#pragma unroll
    for (int d = 0; d < DD; d += 4) {
        float4 s4 = *(const float4*)(srow + d);
        acc += s4.x * q[d] + s4.y * q[d + 1] + s4.z * q[d + 2] + s4.w * q[d + 3];
    }
    proj[b * MM + t] = (_Float16)acc;
}

// K2 (S1): 128x128 tile GEMM, BK=64, fp16 MFMA, keys as first operand.
// Epilogue: per-row block-local max + sum(exp) -> stats only. (r4-measured)
__global__ __launch_bounds__(256, 3)
void stats_kernel(const _Float16* __restrict__ proj,   // [2048][256]
                  const _Float16* __restrict__ kh,     // [32768][256]
                  const float* __restrict__ key_norms,
                  float* __restrict__ stats_max,       // [2048][256]
                  float* __restrict__ stats_sum) {     // [2048][256]
    __shared__ __align__(16) _Float16 smem[16384];   // sQ(16KB) + sK(16KB)
    __shared__ float red[128][2];
    __shared__ float redS[128][2];
    _Float16* sQ = smem;
    _Float16* sK = smem + 8192;

    const int tid  = threadIdx.x;
    const int lane = tid & 63;
    const int wave = tid >> 6;
    const int quad = lane >> 4;
    const int lc   = lane & 15;
    const int wb   = wave >> 1;   // b-row 64-strip
    const int wn   = wave & 1;    // key-col 64-strip
    const int cb      = blockIdx.x;         // key col-block (fastest -> XCD owns keys)
    const int colBase = cb * 128;
    const int rowBase = blockIdx.y * 128;   // batch rows

    floatx4 acc[4][4];   // [ib][in]: C[b=wb*64+ib*16+lc][n=wn*64+in*16+quad*4+r]
#pragma unroll
    for (int i = 0; i < 4; i++)
#pragma unroll
        for (int j = 0; j < 4; j++) acc[i][j] = (floatx4){0.f, 0.f, 0.f, 0.f};

    // Staging: chunk c in [0,1024): LDS slot c*16B (wave-uniform + lane*16),
    // holds global (row=c>>3, seg=(c&7)^(row&7)) -- XOR swizzle balances the
    // ds_read_b128 bank pattern for the 128B row stride.
    const _Float16* gQ[4];
    const _Float16* gK[4];
    int ldsOff[4];
#pragma unroll
    for (int p = 0; p < 4; p++) {
        const int c = p * 256 + tid;
        const int row = c >> 3;
        const int seg = (c & 7) ^ (row & 7);
        gQ[p] = proj + (rowBase + row) * MM + seg * 8;
        gK[p] = kh + (colBase + row) * MM + seg * 8;
        ldsOff[p] = c * 8;
    }

    for (int k0 = 0; k0 < MM; k0 += 64) {
        __syncthreads();
#pragma unroll
        for (int p = 0; p < 4; p++) {
            async16(gQ[p] + k0, &sQ[ldsOff[p]]);
            async16(gK[p] + k0, &sK[ldsOff[p]]);
        }
        __syncthreads();
#pragma unroll
        for (int kk = 0; kk < 2; kk++) {
            const int segSel = ((kk * 4 + quad) ^ (lc & 7)) * 8;
            half8 kf[4], qf[4];
#pragma unroll
            for (int s = 0; s < 4; s++) {
                kf[s] = *(const half8*)&sK[(wn * 64 + s * 16 + lc) * 64 + segSel];
                qf[s] = *(const half8*)&sQ[(wb * 64 + s * 16 + lc) * 64 + segSel];
            }
#pragma unroll
            for (int ib = 0; ib < 4; ib++)
#pragma unroll
                for (int in = 0; in < 4; in++)
                    acc[ib][in] = __builtin_amdgcn_mfma_f32_16x16x32_f16(
                        kf[in], qf[ib], acc[ib][in], 0, 0, 0);
        }
    }

    // scale: s = EST * norm[n] * inner ; n varies with (in, quad, r)
#pragma unroll
    for (int in = 0; in < 4; in++) {
        const float4 nrm = *(const float4*)&key_norms[colBase + wn * 64 + in * 16 + quad * 4];
#pragma unroll
        for (int ib = 0; ib < 4; ib++) {
            acc[ib][in][0] *= EST_CONST * nrm.x;
            acc[ib][in][1] *= EST_CONST * nrm.y;
            acc[ib][in][2] *= EST_CONST * nrm.z;
            acc[ib][in][3] *= EST_CONST * nrm.w;
        }
    }

    // per-row (128-col block-local) max; row owned by lane lc (dup over quads)
#pragma unroll
    for (int ib = 0; ib < 4; ib++) {
        float mx = -1e30f;
#pragma unroll
        for (int in = 0; in < 4; in++)
#pragma unroll
            for (int r = 0; r < 4; r++) mx = fmaxf(mx, acc[ib][in][r]);
        mx = fmaxf(mx, __shfl_xor(mx, 16, 64));
        mx = fmaxf(mx, __shfl_xor(mx, 32, 64));
        if (quad == 0) red[wb * 64 + ib * 16 + lc][wn] = mx;
    }
    __syncthreads();   // red visible
    float mcb[4];
#pragma unroll
    for (int ib = 0; ib < 4; ib++) {
        const int rl = wb * 64 + ib * 16 + lc;
        mcb[ib] = fmaxf(red[rl][0], red[rl][1]);
    }
    // partial sums of exp(s - mcb)
#pragma unroll
    for (int ib = 0; ib < 4; ib++) {
        float sm = 0.f;
#pragma unroll
        for (int in = 0; in < 4; in++)
#pragma unroll
            for (int r = 0; r < 4; r++) sm += __expf(acc[ib][in][r] - mcb[ib]);
        sm += __shfl_xor(sm, 16, 64);
        sm += __shfl_xor(sm, 32, 64);
        if (quad == 0) redS[wb * 64 + ib * 16 + lc][wn] = sm;
    }
    __syncthreads();   // redS visible
    if (wn == 0 && quad == 0) {
#pragma unroll
        for (int ib = 0; ib < 4; ib++) {
            const int rl = wb * 64 + ib * 16 + lc;
            const int grow = rowBase + rl;
            stats_max[grow * 256 + cb] = mcb[ib];
            stats_sum[grow * 256 + cb] = redS[rl][0] + redS[rl][1];
        }
    }
}

// K3: per-row combine of 256 (m, l) -> rowC[row] = M + ln(L), so the output
// pass is a single exp(s - C). One wave per row; butterfly reduce.
__global__ void combine_stats(const float* __restrict__ smax, const float* __restrict__ ssum,
                              float* __restrict__ rowC) {
    const int lane = threadIdx.x & 63;
    const int row = blockIdx.x * 4 + (threadIdx.x >> 6);
    const float4 mv = ((const float4*)(smax + row * 256))[lane];
    float m = fmaxf(fmaxf(mv.x, mv.y), fmaxf(mv.z, mv.w));
#pragma unroll
    for (int d = 1; d < 64; d <<= 1) m = fmaxf(m, __shfl_xor(m, d, 64));
    const float4 sv = ((const float4*)(ssum + row * 256))[lane];
    float l = sv.x * __expf(mv.x - m) + sv.y * __expf(mv.y - m) +
              sv.z * __expf(mv.z - m) + sv.w * __expf(mv.w - m);
#pragma unroll
    for (int d = 1; d < 64; d <<= 1) l += __shfl_xor(l, d, 64);
    if (lane == 0) rowC[row] = m + __logf(l);   // L >= 1 always (contains exp(0))
}

// K4 (S2): recompute the identical GEMM; epilogue applies exp(s - C) and
// stores fp32 out directly (64B-sector aligned segments). (r4-measured)
__global__ __launch_bounds__(256, 3)
void out_kernel(const _Float16* __restrict__ proj,   // [2048][256]
                const _Float16* __restrict__ kh,     // [32768][256]
                const float* __restrict__ key_norms,
                const float* __restrict__ rowC,      // [2048]
                float* __restrict__ out) {           // [2048][32768]
    __shared__ __align__(16) _Float16 smem[16384];
    _Float16* sQ = smem;
    _Float16* sK = smem + 8192;

    const int tid  = threadIdx.x;
    const int lane = tid & 63;
    const int wave = tid >> 6;
    const int quad = lane >> 4;
    const int lc   = lane & 15;
    const int wb   = wave >> 1;
    const int wn   = wave & 1;
    const int cb      = blockIdx.x;
    const int colBase = cb * 128;
    const int rowBase = blockIdx.y * 128;

    floatx4 acc[4][4];
#pragma unroll
    for (int i = 0; i < 4; i++)
#pragma unroll
        for (int j = 0; j < 4; j++) acc[i][j] = (floatx4){0.f, 0.f, 0.f, 0.f};

    const _Float16* gQ[4];
    const _Float16* gK[4];
    int ldsOff[4];
#pragma unroll
    for (int p = 0; p < 4; p++) {
        const int c = p * 256 + tid;
        const int row = c >> 3;
        const int seg = (c & 7) ^ (row & 7);
        gQ[p] = proj + (rowBase + row) * MM + seg * 8;
        gK[p] = kh + (colBase + row) * MM + seg * 8;
        ldsOff[p] = c * 8;
    }

    // hoist per-row softmax constants (4 rows/thread, broadcast in 16-lane groups)
    float cRow[4];
#pragma unroll
    for (int ib = 0; ib < 4; ib++)
        cRow[ib] = rowC[rowBase + wb * 64 + ib * 16 + lc];

    for (int k0 = 0; k0 < MM; k0 += 64) {
        __syncthreads();
#pragma unroll
        for (int p = 0; p < 4; p++) {
            async16(gQ[p] + k0, &sQ[ldsOff[p]]);
            async16(gK[p] + k0, &sK[ldsOff[p]]);
        }
        __syncthreads();
#pragma unroll
        for (int kk = 0; kk < 2; kk++) {
            const int segSel = ((kk * 4 + quad) ^ (lc & 7)) * 8;
            half8 kf[4], qf[4];
#pragma unroll
            for (int s = 0; s < 4; s++) {
                kf[s] = *(const half8*)&sK[(wn * 64 + s * 16 + lc) * 64 + segSel];
                qf[s] = *(const half8*)&sQ[(wb * 64 + s * 16 + lc) * 64 + segSel];
            }
#pragma unroll
            for (int ib = 0; ib < 4; ib++)
#pragma unroll
                for (int in = 0; in < 4; in++)
                    acc[ib][in] = __builtin_amdgcn_mfma_f32_16x16x32_f16(
                        kf[in], qf[ib], acc[ib][in], 0, 0, 0);
        }
    }

    // scale (same FMA ordering as stats_kernel)
#pragma unroll
    for (int in = 0; in < 4; in++) {
        const float4 nrm = *(const float4*)&key_norms[colBase + wn * 64 + in * 16 + quad * 4];
#pragma unroll
        for (int ib = 0; ib < 4; ib++) {
            acc[ib][in][0] *= EST_CONST * nrm.x;
            acc[ib][in][1] *= EST_CONST * nrm.y;
            acc[ib][in][2] *= EST_CONST * nrm.z;
            acc[ib][in][3] *= EST_CONST * nrm.w;
        }
    }

    // out[grow][gcol] = exp(s - C), fp32, nontemporal 16B/lane
#pragma unroll
    for (int ib = 0; ib < 4; ib++) {
        const int grow = rowBase + wb * 64 + ib * 16 + lc;
        const float c = cRow[ib];
        float* orow = out + (size_t)grow * NK + colBase + wn * 64 + quad * 4;
#pragma unroll
        for (int in = 0; in < 4; in++) {
            floatx4 o;
#pragma unroll
            for (int r = 0; r < 4; r++)
                o[r] = __expf(acc[ib][in][r] - c);
            __builtin_nontemporal_store(o, (floatx4*)(orow + in * 16));
        }
    }
}

extern "C" void kernel_launch(void* const* d_in, const int* in_sizes, int n_in,
                              void* d_out, int out_size, void* d_ws, size_t ws_size,
                              hipStream_t stream) {
    const float* query  = (const float*)d_in[0];   // [2048][128]
    const float* keys   = (const float*)d_in[1];   // [32768][256] (+-1)
    const float* norms  = (const float*)d_in[2];   // [32768]
    const float* sketch = (const float*)d_in[3];   // [256][128]
    float* out = (float*)d_out;                    // [2048][32768]

    char* ws = (char*)d_ws;
    const size_t MB = 1024 * 1024;
    _Float16* kh   = (_Float16*)(ws);               // 16 MB
    _Float16* proj = (_Float16*)(ws + 16 * MB);     // 1 MB
    float* smax    = (float*)(ws + 17 * MB);        // 2 MB
    float* ssum    = (float*)(ws + 19 * MB);        // 2 MB
    float* rowC    = (float*)(ws + 21 * MB);        // 8 KB

    hipLaunchKernelGGL(prep_kernel, dim3(8192 + NB), dim3(256), 0, stream,
                       query, sketch, keys, proj, kh);
    hipLaunchKernelGGL(stats_kernel, dim3(NK / 128, NB / 128), dim3(256), 0, stream,
                       proj, kh, norms, smax, ssum);
    hipLaunchKernelGGL(combine_stats, dim3(NB / 4), dim3(256), 0, stream,
                       smax, ssum, rowC);
    hipLaunchKernelGGL(out_kernel, dim3(NK / 128, NB / 128), dim3(256), 0, stream,
                       proj, kh, norms, rowC, out);
}